// Round 2
// baseline (141.931 us; speedup 1.0000x reference)
//
#include <hip/hip_runtime.h>
#include <hip/hip_bf16.h>

typedef __hip_bfloat16 bf16;
#define HW_ 65536

__device__ __forceinline__ float to_f(bf16 v) { return __bfloat162float(v); }
__device__ __forceinline__ float to_f(float v) { return v; }

union bf16x4u { uint2 u; bf16 h[4]; };

template <typename T> struct V4;
template <> struct V4<bf16> {
    static __device__ __forceinline__ void ld(const bf16* p, float o[4]) {
        bf16x4u v; v.u = *(const uint2*)p;
        o[0] = to_f(v.h[0]); o[1] = to_f(v.h[1]);
        o[2] = to_f(v.h[2]); o[3] = to_f(v.h[3]);
    }
    static __device__ __forceinline__ void st(bf16* p, const float v[4]) {
        bf16x4u k;
        k.h[0] = __float2bfloat16(v[0]); k.h[1] = __float2bfloat16(v[1]);
        k.h[2] = __float2bfloat16(v[2]); k.h[3] = __float2bfloat16(v[3]);
        *(uint2*)p = k.u;
    }
};
template <> struct V4<float> {
    static __device__ __forceinline__ void ld(const float* p, float o[4]) {
        float4 v = *(const float4*)p;
        o[0] = v.x; o[1] = v.y; o[2] = v.z; o[3] = v.w;
    }
    static __device__ __forceinline__ void st(float* p, const float v[4]) {
        float4 k; k.x = v[0]; k.y = v[1]; k.z = v[2]; k.w = v[3];
        *(float4*)p = k;
    }
};

// ---- scratch in device globals: independent of ws_size, rewritten fully
// ---- every call (graph-capture safe, no cross-call state reliance)
__device__ int    g_flag;          // 0 = inputs are bf16, 1 = inputs are fp32
__device__ double g_part[128];
__device__ double g_tD[256];
__device__ double g_WgP[32];
__device__ double g_bgP[8];
__device__ float  g_Wm[8192];
__device__ float  g_Bm[2048];

// ---------------------------------------------------------------------------
// Probe: read first 64 elements of Wk1 AS bf16. True bf16 ~N(0,0.05^2):
// max|v| < ~0.3. If buffer is really fp32, half these are random-mantissa
// bit patterns -> max|v| > 4 with P ~= 1 - 2^-32.
// ---------------------------------------------------------------------------
__global__ void k_probe(const bf16* __restrict__ w) {
    int t = threadIdx.x;
    float v = fabsf(to_f(w[t]));
    #pragma unroll
    for (int off = 32; off; off >>= 1) v = fmaxf(v, __shfl_down(v, off));
    if (t == 0) g_flag = (v > 4.0f) ? 1 : 0;
}

// ---------------------------------------------------------------------------
// K1: per-(b,ch) plane sums of raw inputs (fp64). 16 planes x 8 chunks.
// ---------------------------------------------------------------------------
template <typename T>
__global__ void k_sum(const T* __restrict__ rgb, const T* __restrict__ edge,
                      int mode) {
    if (g_flag != mode) return;
    int plane = blockIdx.x;              // b*4 + ch (ch 3 == edge)
    int chunk = blockIdx.y;              // 0..7
    int b = plane >> 2, ch = plane & 3;
    const T* src = (ch < 3) ? rgb + (size_t)(b * 3 + ch) * HW_
                            : edge + (size_t)b * HW_;
    src += chunk * 8192;
    int t = threadIdx.x;
    double s = 0.0;
    #pragma unroll
    for (int p = 0; p < 8; ++p) {
        float v[4];
        V4<T>::ld(src + (p * 256 + t) * 4, v);
        s += (double)v[0] + (double)v[1] + (double)v[2] + (double)v[3];
    }
    #pragma unroll
    for (int off = 32; off; off >>= 1) s += __shfl_down(s, off);
    __shared__ double wsum[4];
    if ((t & 63) == 0) wsum[t >> 6] = s;
    __syncthreads();
    if (t == 0) g_part[plane * 8 + chunk] = wsum[0] + wsum[1] + wsum[2] + wsum[3];
}

// ---------------------------------------------------------------------------
// K2a: means -> g -> t = sigmoid(Wk1 g + bk1); collapsed guide weights (fp64).
// ---------------------------------------------------------------------------
template <typename T>
__global__ void k_params_a(const T* __restrict__ W1, const T* __restrict__ b1,
                           const T* __restrict__ Wk1, const T* __restrict__ bk1,
                           const T* __restrict__ Wg, const T* __restrict__ bg,
                           int mode) {
    if (g_flag != mode) return;
    __shared__ double xm[16];
    __shared__ double g[256];
    int t = threadIdx.x;
    if (t < 16) {
        double s = 0;
        #pragma unroll
        for (int i = 0; i < 8; ++i) s += g_part[t * 8 + i];
        xm[t] = s * (1.0 / 65536.0);
    }
    __syncthreads();
    {   // g[b][c] = b1[c] + sum_j W1[c][j] * mean_x[b][j]
        int b = t >> 6, c = t & 63;
        double acc = (double)to_f(b1[c]);
        #pragma unroll
        for (int j = 0; j < 4; ++j)
            acc += (double)to_f(W1[c * 4 + j]) * xm[b * 4 + j];
        g[t] = acc;
    }
    __syncthreads();
    {   // t[b][j] = sigmoid(bk1[j] + sum_c Wk1[j][c] g[b][c])
        int b = t >> 6, j = t & 63;
        double z = (double)to_f(bk1[j]);
        for (int c = 0; c < 64; ++c)
            z += (double)to_f(Wk1[j * 64 + c]) * g[b * 64 + c];
        g_tD[t] = 1.0 / (1.0 + exp(-z));
    }
    if (t < 32) {        // WgP[r][j] = sum_c Wg[r][c] W1[c][j]
        int r = t >> 2, j = t & 3;
        double a = 0;
        for (int c = 0; c < 64; ++c)
            a += (double)to_f(Wg[r * 64 + c]) * (double)to_f(W1[c * 4 + j]);
        g_WgP[t] = a;
    } else if (t < 40) { // bgP[r] = bg[r] + sum_c Wg[r][c] b1[c]
        int r = t - 32;
        double a = (double)to_f(bg[r]);
        for (int c = 0; c < 64; ++c)
            a += (double)to_f(Wg[r * 64 + c]) * (double)to_f(b1[c]);
        g_bgP[r] = a;
    }
}

// ---------------------------------------------------------------------------
// K2b: generate per-(b,region) 64x64 kernel, collapse to 64x4 weights + bias.
// grid 32 = b*8+gr, 64 threads (thread = output channel o).
// ---------------------------------------------------------------------------
template <typename T>
__global__ void k_params_b(const T* __restrict__ W1, const T* __restrict__ b1,
                           const T* __restrict__ Wk2, const T* __restrict__ bk2,
                           int mode) {
    if (g_flag != mode) return;
    int blk = blockIdx.x;          // b*8 + gr
    int b = blk >> 3, gr = blk & 7;
    int o = threadIdx.x;           // 0..63
    double tt[8];
    #pragma unroll
    for (int i = 0; i < 8; ++i) tt[i] = g_tD[b * 64 + gr * 8 + i];
    double aw0 = 0, aw1 = 0, aw2 = 0, aw3 = 0, ab = 0;
    const T* wk2p = Wk2 + ((size_t)gr * 4096 + o * 64) * 8;
    const T* bk2p = bk2 + (size_t)gr * 4096 + o * 64;
    for (int c = 0; c < 64; ++c) {
        double ker = (double)to_f(bk2p[c]);
        #pragma unroll
        for (int i = 0; i < 8; ++i)
            ker += tt[i] * (double)to_f(wk2p[c * 8 + i]);
        aw0 += ker * (double)to_f(W1[c * 4 + 0]);
        aw1 += ker * (double)to_f(W1[c * 4 + 1]);
        aw2 += ker * (double)to_f(W1[c * 4 + 2]);
        ab  += ker * (double)to_f(b1[c]);
        aw3 += ker * (double)to_f(W1[c * 4 + 3]);
    }
    float* w = g_Wm + ((size_t)blk * 64 + o) * 4;
    w[0] = (float)aw0; w[1] = (float)aw1; w[2] = (float)aw2; w[3] = (float)aw3;
    g_Bm[blk * 64 + o] = (float)ab;
}

// ---------------------------------------------------------------------------
// K3: per-pixel guide argmax + collapsed 64x4 matvec. 4 px/thread.
// LDS region stride 1028 floats -> region r starts at bank 4r (conflict-free
// for 8-way region-divergent b128 reads; same-region lanes broadcast).
// ---------------------------------------------------------------------------
template <typename T>
__launch_bounds__(256)
__global__ void k_main(const T* __restrict__ rgb, const T* __restrict__ edge,
                       T* __restrict__ out, int mode) {
    if (g_flag != mode) return;
    __shared__ __align__(16) float sW[8 * 1028];
    __shared__ __align__(16) float sB[8 * 68];
    __shared__ double sWg[32];
    __shared__ double sBg[8];
    int t = threadIdx.x;
    int b = blockIdx.y;

    {   // stage this batch's collapsed kernels
        const float4* src = (const float4*)(g_Wm + (size_t)b * 2048);
        #pragma unroll
        for (int k = 0; k < 2; ++k) {
            int idx = t + 256 * k; int r = idx >> 6, o = idx & 63;
            *(float4*)&sW[r * 1028 + o * 4] = src[idx];
        }
        const float* bs = g_Bm + (size_t)b * 512;
        #pragma unroll
        for (int k = 0; k < 2; ++k) {
            int idx = t + 256 * k; int r = idx >> 6, o = idx & 63;
            sB[r * 68 + o] = bs[idx];
        }
        if (t < 32) sWg[t] = g_WgP[t];
        else if (t < 40) sBg[t - 32] = g_bgP[t - 32];
    }
    __syncthreads();

    // guide weights in registers (fully unrolled -> VGPRs)
    float wg[32], bgf[8];
    #pragma unroll
    for (int i = 0; i < 32; ++i) wg[i] = (float)sWg[i];
    #pragma unroll
    for (int r = 0; r < 8; ++r) bgf[r] = (float)sBg[r];

    int pxb = (blockIdx.x * 256 + t) * 4;
    float xa[4], xb[4], xc[4], xd[4];
    {
        float v0[4], v1[4], v2[4], v3[4];
        V4<T>::ld(rgb  + (size_t)(b * 3 + 0) * HW_ + pxb, v0);
        V4<T>::ld(rgb  + (size_t)(b * 3 + 1) * HW_ + pxb, v1);
        V4<T>::ld(rgb  + (size_t)(b * 3 + 2) * HW_ + pxb, v2);
        V4<T>::ld(edge + (size_t)b * HW_ + pxb, v3);
        #pragma unroll
        for (int p = 0; p < 4; ++p) {
            xa[p] = v0[p]; xb[p] = v1[p]; xc[p] = v2[p]; xd[p] = v3[p];
        }
    }

    // region argmax: fp32 fast path, fp64 refine on near-ties (first-max wins)
    int reg[4];
    #pragma unroll
    for (int p = 0; p < 4; ++p) {
        float m1 = -1e30f, m2 = -1e30f; int bi = 0;
        #pragma unroll
        for (int r = 0; r < 8; ++r) {
            float gv = bgf[r] + wg[r * 4 + 0] * xa[p] + wg[r * 4 + 1] * xb[p]
                              + wg[r * 4 + 2] * xc[p] + wg[r * 4 + 3] * xd[p];
            if (gv > m1) { m2 = m1; m1 = gv; bi = r; }
            else if (gv > m2) { m2 = gv; }
        }
        if (m1 - m2 < 1e-4f) {
            double da = xa[p], db = xb[p], dc = xc[p], dd = xd[p];
            double bm = -1e300; bi = 0;
            #pragma unroll
            for (int r = 0; r < 8; ++r) {
                double gv = sBg[r] + sWg[r * 4 + 0] * da + sWg[r * 4 + 1] * db
                                   + sWg[r * 4 + 2] * dc + sWg[r * 4 + 3] * dd;
                if (gv > bm) { bm = gv; bi = r; }
            }
        }
        reg[p] = bi;
    }

    int base[4], bbase[4];
    #pragma unroll
    for (int p = 0; p < 4; ++p) { base[p] = reg[p] * 1028; bbase[p] = reg[p] * 68; }

    T* outp = out + (size_t)b * 64 * HW_ + pxb;
    #pragma unroll 4
    for (int oq = 0; oq < 16; ++oq) {
        float res[4][4];                       // [k within quad][px]
        #pragma unroll
        for (int p = 0; p < 4; ++p) {
            float4 bq = *(const float4*)&sB[bbase[p] + oq * 4];
            float bqa[4] = {bq.x, bq.y, bq.z, bq.w};
            #pragma unroll
            for (int k = 0; k < 4; ++k) {
                float4 w = *(const float4*)&sW[base[p] + (oq * 4 + k) * 4];
                res[k][p] = bqa[k] + w.x * xa[p] + w.y * xb[p]
                                   + w.z * xc[p] + w.w * xd[p];
            }
        }
        #pragma unroll
        for (int k = 0; k < 4; ++k) {
            int o = oq * 4 + k;
            V4<T>::st(outp + (size_t)o * HW_, res[k]);
        }
    }
}

// ---------------------------------------------------------------------------
extern "C" void kernel_launch(void* const* d_in, const int* in_sizes, int n_in,
                              void* d_out, int out_size, void* d_ws, size_t ws_size,
                              hipStream_t stream) {
    (void)d_ws; (void)ws_size;

    k_probe<<<1, 64, 0, stream>>>((const bf16*)d_in[4]);

    // bf16 instantiation (mode 0)
    k_sum<bf16><<<dim3(16, 8), 256, 0, stream>>>(
        (const bf16*)d_in[0], (const bf16*)d_in[1], 0);
    k_params_a<bf16><<<1, 256, 0, stream>>>(
        (const bf16*)d_in[2], (const bf16*)d_in[3], (const bf16*)d_in[4],
        (const bf16*)d_in[5], (const bf16*)d_in[8], (const bf16*)d_in[9], 0);
    k_params_b<bf16><<<32, 64, 0, stream>>>(
        (const bf16*)d_in[2], (const bf16*)d_in[3], (const bf16*)d_in[6],
        (const bf16*)d_in[7], 0);
    k_main<bf16><<<dim3(64, 4), 256, 0, stream>>>(
        (const bf16*)d_in[0], (const bf16*)d_in[1], (bf16*)d_out, 0);

    // fp32 instantiation (mode 1)
    k_sum<float><<<dim3(16, 8), 256, 0, stream>>>(
        (const float*)d_in[0], (const float*)d_in[1], 1);
    k_params_a<float><<<1, 256, 0, stream>>>(
        (const float*)d_in[2], (const float*)d_in[3], (const float*)d_in[4],
        (const float*)d_in[5], (const float*)d_in[8], (const float*)d_in[9], 1);
    k_params_b<float><<<32, 64, 0, stream>>>(
        (const float*)d_in[2], (const float*)d_in[3], (const float*)d_in[6],
        (const float*)d_in[7], 1);
    k_main<float><<<dim3(64, 4), 256, 0, stream>>>(
        (const float*)d_in[0], (const float*)d_in[1], (float*)d_out, 1);
}

// Round 7
// 132.416 us; speedup vs baseline: 1.0719x; 1.0719x over previous
//
#include <hip/hip_runtime.h>
#include <hip/hip_bf16.h>

// Inputs/outputs are fp32 STORAGE (values bf16-quantized by the harness).
// Proven in R2: the fp32 instantiation passed (absmax = 1 output ulp);
// R6 (bf16-only) wrote nothing -> probe had selected fp32. R3-R5 NaNs were
// fp32-read-as-bf16, not sync bugs.

#define HW_ 65536

// device-global scratch — rewritten fully every call; cross-kernel
// visibility via kernel-boundary ordering (R2-proven).
__device__ double g_part[128];
__device__ double g_tD[256];
__device__ double g_WgP[32];
__device__ double g_bgP[8];
__device__ float  g_Wm[8192];   // [b*8+gr][o][j] collapsed 64x4 weights
__device__ float  g_Bm[2048];   // [b*8+gr][o]    collapsed bias

// ---------------------------------------------------------------------------
// K1: per-(b,ch) plane sums of raw inputs (fp64). 16 planes x 8 chunks.
// ---------------------------------------------------------------------------
__global__ void k_sum(const float* __restrict__ rgb, const float* __restrict__ edge) {
    int plane = blockIdx.x;              // b*4 + ch (ch 3 == edge)
    int chunk = blockIdx.y;              // 0..7
    int b = plane >> 2, ch = plane & 3;
    const float* src = (ch < 3) ? rgb + (size_t)(b * 3 + ch) * HW_
                                : edge + (size_t)b * HW_;
    src += chunk * 8192;
    int t = threadIdx.x;
    double s = 0.0;
    #pragma unroll
    for (int p = 0; p < 8; ++p) {
        float4 v = *(const float4*)(src + (p * 256 + t) * 4);
        s += (double)v.x + (double)v.y + (double)v.z + (double)v.w;
    }
    #pragma unroll
    for (int off = 32; off; off >>= 1) s += __shfl_down(s, off);
    __shared__ double wsum[4];
    if ((t & 63) == 0) wsum[t >> 6] = s;
    __syncthreads();
    if (t == 0) g_part[plane * 8 + chunk] = wsum[0] + wsum[1] + wsum[2] + wsum[3];
}

// ---------------------------------------------------------------------------
// K2a: means -> g -> t = sigmoid(Wk1 g + bk1); collapsed guide weights (fp64).
// ---------------------------------------------------------------------------
__global__ void k_params_a(const float* __restrict__ W1, const float* __restrict__ b1,
                           const float* __restrict__ Wk1, const float* __restrict__ bk1,
                           const float* __restrict__ Wg, const float* __restrict__ bg) {
    __shared__ double xm[16];
    __shared__ double g[256];
    int t = threadIdx.x;
    if (t < 16) {
        double s = 0;
        #pragma unroll
        for (int i = 0; i < 8; ++i) s += g_part[t * 8 + i];
        xm[t] = s * (1.0 / 65536.0);
    }
    __syncthreads();
    {   // g[b][c] = b1[c] + sum_j W1[c][j] * mean_x[b][j]
        int b = t >> 6, c = t & 63;
        double acc = (double)b1[c];
        #pragma unroll
        for (int j = 0; j < 4; ++j)
            acc += (double)W1[c * 4 + j] * xm[b * 4 + j];
        g[t] = acc;
    }
    __syncthreads();
    {   // t[b][j] = sigmoid(bk1[j] + sum_c Wk1[j][c] g[b][c])
        int b = t >> 6, j = t & 63;
        double z = (double)bk1[j];
        for (int c = 0; c < 64; ++c)
            z += (double)Wk1[j * 64 + c] * g[b * 64 + c];
        g_tD[t] = 1.0 / (1.0 + exp(-z));
    }
    if (t < 32) {        // WgP[r][j] = sum_c Wg[r][c] W1[c][j]
        int r = t >> 2, j = t & 3;
        double a = 0;
        for (int c = 0; c < 64; ++c)
            a += (double)Wg[r * 64 + c] * (double)W1[c * 4 + j];
        g_WgP[t] = a;
    } else if (t < 40) { // bgP[r] = bg[r] + sum_c Wg[r][c] b1[c]
        int r = t - 32;
        double a = (double)bg[r];
        for (int c = 0; c < 64; ++c)
            a += (double)Wg[r * 64 + c] * (double)b1[c];
        g_bgP[r] = a;
    }
}

// ---------------------------------------------------------------------------
// K2b: generate per-(b,region) 64x64 kernel, collapse to 64x4 weights + bias.
// grid 32 = b*8+gr, 64 threads (thread = output channel o).
// ---------------------------------------------------------------------------
__global__ void k_params_b(const float* __restrict__ W1, const float* __restrict__ b1,
                           const float* __restrict__ Wk2, const float* __restrict__ bk2) {
    int blk = blockIdx.x;          // b*8 + gr
    int b = blk >> 3, gr = blk & 7;
    int o = threadIdx.x;           // 0..63
    double tt[8];
    #pragma unroll
    for (int i = 0; i < 8; ++i) tt[i] = g_tD[b * 64 + gr * 8 + i];
    double aw0 = 0, aw1 = 0, aw2 = 0, aw3 = 0, ab = 0;
    const float* wk2p = Wk2 + ((size_t)gr * 4096 + o * 64) * 8;
    const float* bk2p = bk2 + (size_t)gr * 4096 + o * 64;
    for (int c = 0; c < 64; ++c) {
        double ker = (double)bk2p[c];
        #pragma unroll
        for (int i = 0; i < 8; ++i)
            ker += tt[i] * (double)wk2p[c * 8 + i];
        aw0 += ker * (double)W1[c * 4 + 0];
        aw1 += ker * (double)W1[c * 4 + 1];
        aw2 += ker * (double)W1[c * 4 + 2];
        ab  += ker * (double)b1[c];
        aw3 += ker * (double)W1[c * 4 + 3];
    }
    float* w = g_Wm + ((size_t)blk * 64 + o) * 4;
    w[0] = (float)aw0; w[1] = (float)aw1; w[2] = (float)aw2; w[3] = (float)aw3;
    g_Bm[blk * 64 + o] = (float)ab;
}

// ---------------------------------------------------------------------------
// K3: per-pixel guide argmax + collapsed 64x4 matvec. 4 px/thread.
// LDS region stride 1028 floats -> region r starts at bank 4r (conflict-free
// for 8-way region-divergent b128 reads; same-region lanes broadcast).
// ---------------------------------------------------------------------------
__launch_bounds__(256)
__global__ void k_main(const float* __restrict__ rgb, const float* __restrict__ edge,
                       float* __restrict__ out) {
    __shared__ __align__(16) float sW[8 * 1028];
    __shared__ __align__(16) float sB[8 * 68];
    __shared__ double sWg[32];
    __shared__ double sBg[8];
    int t = threadIdx.x;
    int b = blockIdx.y;

    {   // stage this batch's collapsed kernels
        const float4* src = (const float4*)(g_Wm + (size_t)b * 2048);
        #pragma unroll
        for (int k = 0; k < 2; ++k) {
            int idx = t + 256 * k; int r = idx >> 6, o = idx & 63;
            *(float4*)&sW[r * 1028 + o * 4] = src[idx];
        }
        const float* bs = g_Bm + (size_t)b * 512;
        #pragma unroll
        for (int k = 0; k < 2; ++k) {
            int idx = t + 256 * k; int r = idx >> 6, o = idx & 63;
            sB[r * 68 + o] = bs[idx];
        }
        if (t < 32) sWg[t] = g_WgP[t];
        else if (t < 40) sBg[t - 32] = g_bgP[t - 32];
    }
    __syncthreads();

    // guide weights in registers (fully unrolled -> VGPRs)
    float wg[32], bgf[8];
    #pragma unroll
    for (int i = 0; i < 32; ++i) wg[i] = (float)sWg[i];
    #pragma unroll
    for (int r = 0; r < 8; ++r) bgf[r] = (float)sBg[r];

    int pxb = (blockIdx.x * 256 + t) * 4;
    float xa[4], xb[4], xc[4], xd[4];
    {
        float4 v0 = *(const float4*)(rgb  + (size_t)(b * 3 + 0) * HW_ + pxb);
        float4 v1 = *(const float4*)(rgb  + (size_t)(b * 3 + 1) * HW_ + pxb);
        float4 v2 = *(const float4*)(rgb  + (size_t)(b * 3 + 2) * HW_ + pxb);
        float4 v3 = *(const float4*)(edge + (size_t)b * HW_ + pxb);
        xa[0] = v0.x; xa[1] = v0.y; xa[2] = v0.z; xa[3] = v0.w;
        xb[0] = v1.x; xb[1] = v1.y; xb[2] = v1.z; xb[3] = v1.w;
        xc[0] = v2.x; xc[1] = v2.y; xc[2] = v2.z; xc[3] = v2.w;
        xd[0] = v3.x; xd[1] = v3.y; xd[2] = v3.z; xd[3] = v3.w;
    }

    // region argmax: fp32 fast path, fp64 refine on near-ties (first-max wins)
    int reg[4];
    #pragma unroll
    for (int p = 0; p < 4; ++p) {
        float m1 = -1e30f, m2 = -1e30f; int bi = 0;
        #pragma unroll
        for (int r = 0; r < 8; ++r) {
            float gv = bgf[r] + wg[r * 4 + 0] * xa[p] + wg[r * 4 + 1] * xb[p]
                              + wg[r * 4 + 2] * xc[p] + wg[r * 4 + 3] * xd[p];
            if (gv > m1) { m2 = m1; m1 = gv; bi = r; }
            else if (gv > m2) { m2 = gv; }
        }
        if (m1 - m2 < 1e-4f) {
            double da = xa[p], db = xb[p], dc = xc[p], dd = xd[p];
            double bm = -1e300; bi = 0;
            #pragma unroll
            for (int r = 0; r < 8; ++r) {
                double gv = sBg[r] + sWg[r * 4 + 0] * da + sWg[r * 4 + 1] * db
                                   + sWg[r * 4 + 2] * dc + sWg[r * 4 + 3] * dd;
                if (gv > bm) { bm = gv; bi = r; }
            }
        }
        reg[p] = bi;
    }

    int base[4], bbase[4];
    #pragma unroll
    for (int p = 0; p < 4; ++p) { base[p] = reg[p] * 1028; bbase[p] = reg[p] * 68; }

    float* outp = out + (size_t)b * 64 * HW_ + pxb;
    #pragma unroll 4
    for (int oq = 0; oq < 16; ++oq) {
        float res[4][4];                       // [k within quad][px]
        #pragma unroll
        for (int p = 0; p < 4; ++p) {
            float4 bq = *(const float4*)&sB[bbase[p] + oq * 4];
            float bqa[4] = {bq.x, bq.y, bq.z, bq.w};
            #pragma unroll
            for (int k = 0; k < 4; ++k) {
                float4 w = *(const float4*)&sW[base[p] + (oq * 4 + k) * 4];
                res[k][p] = bqa[k] + w.x * xa[p] + w.y * xb[p]
                                   + w.z * xc[p] + w.w * xd[p];
            }
        }
        #pragma unroll
        for (int k = 0; k < 4; ++k) {
            int o = oq * 4 + k;
            float4 pk; pk.x = res[k][0]; pk.y = res[k][1];
            pk.z = res[k][2]; pk.w = res[k][3];
            *(float4*)(outp + (size_t)o * HW_) = pk;
        }
    }
}

// ---------------------------------------------------------------------------
extern "C" void kernel_launch(void* const* d_in, const int* in_sizes, int n_in,
                              void* d_out, int out_size, void* d_ws, size_t ws_size,
                              hipStream_t stream) {
    (void)d_ws; (void)ws_size;
    const float* rgb  = (const float*)d_in[0];
    const float* edge = (const float*)d_in[1];
    const float* W1   = (const float*)d_in[2];
    const float* b1   = (const float*)d_in[3];
    const float* Wk1  = (const float*)d_in[4];
    const float* bk1  = (const float*)d_in[5];
    const float* Wk2  = (const float*)d_in[6];
    const float* bk2  = (const float*)d_in[7];
    const float* Wg   = (const float*)d_in[8];
    const float* bg   = (const float*)d_in[9];
    float* out = (float*)d_out;

    k_sum<<<dim3(16, 8), 256, 0, stream>>>(rgb, edge);
    k_params_a<<<1, 256, 0, stream>>>(W1, b1, Wk1, bk1, Wg, bg);
    k_params_b<<<32, 64, 0, stream>>>(W1, b1, Wk2, bk2);
    k_main<<<dim3(64, 4), 256, 0, stream>>>(rgb, edge, out);
}